// Round 1
// baseline (3382.386 us; speedup 1.0000x reference)
//
#include <hip/hip_runtime.h>
#include <cstddef>

#define N_NODES 16384
#define N_GRAPHS 64
#define NPG 256
#define F_IN 128
#define E_DIM 256
#define N_HEADS 8
#define DH 32
#define MLP 1024
#define N_LAYERS 4
#define N_CLASSES 10
#define N_EDGES 262144
#define S_LEN 257
#define M_ROWS (N_GRAPHS * S_LEN)   // 16448
#define LN_EPS 1e-5f

// ---------------- generic GEMM: C(M,N) = A(M,K) @ B(N,K)^T (+bias)(+add)(relu?) -----
// 64x64 tile, BK=16, 256 threads, 4x4 microtile per thread. M,N % 64 == 0, K % 16 == 0.
__global__ __launch_bounds__(256) void gemm_abt(
    const float* __restrict__ A, const float* __restrict__ B,
    const float* __restrict__ bias, const float* __restrict__ add,
    float* __restrict__ C, int M, int N, int K, int relu)
{
    __shared__ float As[16][65];
    __shared__ float Bs[16][65];
    const int tid = threadIdx.x;
    const int bm = blockIdx.y * 64;
    const int bn = blockIdx.x * 64;
    const int tx = tid & 15, ty = tid >> 4;
    const int lr = tid >> 2;          // 0..63 row in tile
    const int lk = (tid & 3) * 4;     // 0,4,8,12

    float acc[4][4] = {{0.f}};

    for (int k0 = 0; k0 < K; k0 += 16) {
        const float4 a4 = *(const float4*)(A + (size_t)(bm + lr) * K + k0 + lk);
        const float4 b4 = *(const float4*)(B + (size_t)(bn + lr) * K + k0 + lk);
        __syncthreads();
        As[lk + 0][lr] = a4.x; As[lk + 1][lr] = a4.y; As[lk + 2][lr] = a4.z; As[lk + 3][lr] = a4.w;
        Bs[lk + 0][lr] = b4.x; Bs[lk + 1][lr] = b4.y; Bs[lk + 2][lr] = b4.z; Bs[lk + 3][lr] = b4.w;
        __syncthreads();
#pragma unroll
        for (int kk = 0; kk < 16; ++kk) {
            float av[4], bv[4];
#pragma unroll
            for (int i = 0; i < 4; ++i) av[i] = As[kk][ty * 4 + i];
#pragma unroll
            for (int j = 0; j < 4; ++j) bv[j] = Bs[kk][tx * 4 + j];
#pragma unroll
            for (int i = 0; i < 4; ++i)
#pragma unroll
                for (int j = 0; j < 4; ++j)
                    acc[i][j] += av[i] * bv[j];
        }
    }

#pragma unroll
    for (int i = 0; i < 4; ++i) {
        const int m = bm + ty * 4 + i;
#pragma unroll
        for (int j = 0; j < 4; ++j) {
            const int n = bn + tx * 4 + j;
            float v = acc[i][j];
            if (bias) v += bias[n];
            if (add)  v += add[(size_t)m * N + n];
            if (relu) v = fmaxf(v, 0.f);
            C[(size_t)m * N + n] = v;
        }
    }
}

// ---------------- GCN pieces ----------------
__global__ void deg_count(const int* __restrict__ ei, float* __restrict__ deg) {
    int e = blockIdx.x * blockDim.x + threadIdx.x;
    if (e < N_EDGES) atomicAdd(&deg[ei[N_EDGES + e]], 1.0f);
}

__global__ void make_dinv(float* __restrict__ deg) {
    int i = blockIdx.x * blockDim.x + threadIdx.x;
    if (i < N_NODES) deg[i] = rsqrtf(deg[i] + 1.0f);  // +1 self loop
}

__global__ void edge_agg(const float* __restrict__ xw, const float* __restrict__ dinv,
                         const int* __restrict__ ei, float* __restrict__ agg) {
    int e = blockIdx.x;
    int f = threadIdx.x;  // 128
    int r = ei[e];
    int c = ei[N_EDGES + e];
    float nrm = dinv[r] * dinv[c];
    atomicAdd(&agg[(size_t)c * F_IN + f], nrm * xw[(size_t)r * F_IN + f]);
}

__global__ void gcn_finish(float* __restrict__ agg, const float* __restrict__ xw,
                           const float* __restrict__ dinv, const float* __restrict__ b) {
    int i = blockIdx.x;
    int f = threadIdx.x;  // 128
    float di = dinv[i];
    size_t idx = (size_t)i * F_IN + f;
    float v = agg[idx] + di * di * xw[idx] + b[f];
    agg[idx] = fmaxf(v, 0.f);
}

// ---------------- h assembly ----------------
__global__ void assemble_h(const float* __restrict__ emb, const float* __restrict__ cls,
                           float* __restrict__ h) {
    int row = blockIdx.x;            // 0..16447
    int f = threadIdx.x;             // 256
    int g = row / S_LEN, s = row % S_LEN;
    h[(size_t)row * E_DIM + f] = (s == 0) ? cls[f] : emb[((size_t)g * NPG + (s - 1)) * E_DIM + f];
}

// ---------------- attention: one block per (graph, head) ----------------
__global__ __launch_bounds__(320) void attn(const float* __restrict__ qkv, float* __restrict__ o) {
    const int g = blockIdx.x >> 3;
    const int hh = blockIdx.x & 7;
    __shared__ float ks[S_LEN][DH];
    __shared__ float vs[S_LEN][DH];
    const float* base = qkv + (size_t)g * S_LEN * 768;
    for (int idx = threadIdx.x; idx < S_LEN * DH; idx += 320) {
        int s = idx >> 5, d = idx & 31;
        ks[s][d] = base[(size_t)s * 768 + 256 + hh * DH + d];
        vs[s][d] = base[(size_t)s * 768 + 512 + hh * DH + d];
    }
    __syncthreads();
    const int r = threadIdx.x;
    if (r < S_LEN) {
        float q[DH];
#pragma unroll
        for (int d = 0; d < DH; ++d) q[d] = base[(size_t)r * 768 + hh * DH + d];
        const float scale = 0.17677669529663687f;  // 1/sqrt(32)
        float m = -1e30f, l = 0.f;
        float acc[DH];
#pragma unroll
        for (int d = 0; d < DH; ++d) acc[d] = 0.f;
        for (int s = 0; s < S_LEN; ++s) {
            float dot = 0.f;
#pragma unroll
            for (int d = 0; d < DH; ++d) dot += q[d] * ks[s][d];
            dot *= scale;
            float mn = fmaxf(m, dot);
            float alpha = __expf(m - mn);
            float p = __expf(dot - mn);
            l = l * alpha + p;
#pragma unroll
            for (int d = 0; d < DH; ++d) acc[d] = acc[d] * alpha + p * vs[s][d];
            m = mn;
        }
        float inv = 1.f / l;
        float* orow = o + ((size_t)g * S_LEN + r) * E_DIM + hh * DH;
#pragma unroll
        for (int d = 0; d < DH; ++d) orow[d] = acc[d] * inv;
    }
}

// ---------------- LayerNorm(h + res) in-place on h ----------------
__global__ __launch_bounds__(256) void ln_residual(float* __restrict__ h, const float* __restrict__ res,
                                                   const float* __restrict__ g, const float* __restrict__ b) {
    __shared__ float ws1[4], ws2[4];
    __shared__ float mu_s, rstd_s;
    const int row = blockIdx.x;
    const int t = threadIdx.x;
    size_t idx = (size_t)row * E_DIM + t;
    float v = h[idx] + res[idx];
    float s1 = v, s2 = v * v;
#pragma unroll
    for (int off = 32; off > 0; off >>= 1) {
        s1 += __shfl_down(s1, off, 64);
        s2 += __shfl_down(s2, off, 64);
    }
    int wid = t >> 6, lane = t & 63;
    if (lane == 0) { ws1[wid] = s1; ws2[wid] = s2; }
    __syncthreads();
    if (t == 0) {
        float a1 = ws1[0] + ws1[1] + ws1[2] + ws1[3];
        float a2 = ws2[0] + ws2[1] + ws2[2] + ws2[3];
        float mu = a1 * (1.f / 256.f);
        float var = a2 * (1.f / 256.f) - mu * mu;
        mu_s = mu;
        rstd_s = rsqrtf(var + LN_EPS);
    }
    __syncthreads();
    h[idx] = (v - mu_s) * rstd_s * g[t] + b[t];
}

// ---------------- final classifier ----------------
__global__ void fc_kernel(const float* __restrict__ h, const float* __restrict__ w,
                          const float* __restrict__ b, float* __restrict__ out) {
    int g = blockIdx.x;
    __shared__ float row[E_DIM];
    int t = threadIdx.x;
    row[t] = h[(size_t)g * S_LEN * E_DIM + t];
    __syncthreads();
    if (t < N_CLASSES) {
        float s = 0.f;
        for (int j = 0; j < E_DIM; ++j) s += row[j] * w[t * E_DIM + j];
        out[g * N_CLASSES + t] = s + b[t];
    }
}

extern "C" void kernel_launch(void* const* d_in, const int* in_sizes, int n_in,
                              void* d_out, int out_size, void* d_ws, size_t ws_size,
                              hipStream_t stream) {
    const float* x       = (const float*)d_in[0];
    const int*   edgei   = (const int*)  d_in[1];
    // d_in[2] = batch (unused; implied by reshape)
    const float* pos_enc = (const float*)d_in[3];
    const float* gcn_w   = (const float*)d_in[4];
    const float* gcn_b   = (const float*)d_in[5];
    const float* cls     = (const float*)d_in[6];
    const float* emb_w   = (const float*)d_in[7];
    const float* emb_b   = (const float*)d_in[8];
    const float* in_w    = (const float*)d_in[9];
    const float* in_b    = (const float*)d_in[10];
    const float* out_w   = (const float*)d_in[11];
    const float* out_b   = (const float*)d_in[12];
    const float* lin1_w  = (const float*)d_in[13];
    const float* lin1_b  = (const float*)d_in[14];
    const float* lin2_w  = (const float*)d_in[15];
    const float* lin2_b  = (const float*)d_in[16];
    const float* ln1_g   = (const float*)d_in[17];
    const float* ln1_be  = (const float*)d_in[18];
    const float* ln2_g   = (const float*)d_in[19];
    const float* ln2_be  = (const float*)d_in[20];
    const float* fc_w    = (const float*)d_in[21];
    const float* fc_b    = (const float*)d_in[22];
    float* out = (float*)d_out;

    // workspace layout (floats)
    float* ws = (float*)d_ws;
    const size_t H_SZ    = (size_t)M_ROWS * E_DIM;     // 4,210,688
    const size_t QKV_SZ  = (size_t)M_ROWS * 768;       // 12,632,064
    const size_t F_SZ    = (size_t)M_ROWS * MLP;       // 16,842,752
    float* h     = ws;
    float* qkv   = h + H_SZ;
    float* attno = qkv + QKV_SZ;
    float* tmp   = attno + H_SZ;
    float* fbuf  = tmp + H_SZ;
    // aliases (used only before transformer layers start)
    float* deg     = tmp;                                   // 16384 floats
    float* xw      = fbuf;                                  // 16384*128
    float* agg     = fbuf + (size_t)N_NODES * F_IN;         // 16384*128
    float* emb_out = qkv;                                   // 16384*256

    // ---- GCN ----
    hipMemsetAsync(deg, 0, N_NODES * sizeof(float), stream);
    hipMemsetAsync(agg, 0, (size_t)N_NODES * F_IN * sizeof(float), stream);
    deg_count<<<(N_EDGES + 255) / 256, 256, 0, stream>>>(edgei, deg);
    make_dinv<<<(N_NODES + 255) / 256, 256, 0, stream>>>(deg);
    gemm_abt<<<dim3(F_IN / 64, N_NODES / 64), 256, 0, stream>>>(
        x, gcn_w, nullptr, nullptr, xw, N_NODES, F_IN, F_IN, 0);
    edge_agg<<<N_EDGES, F_IN, 0, stream>>>(xw, deg, edgei, agg);
    gcn_finish<<<N_NODES, F_IN, 0, stream>>>(agg, xw, deg, gcn_b);

    // ---- embedding + pos_enc ----
    gemm_abt<<<dim3(E_DIM / 64, N_NODES / 64), 256, 0, stream>>>(
        agg, emb_w, emb_b, pos_enc, emb_out, N_NODES, E_DIM, F_IN, 0);
    assemble_h<<<M_ROWS, E_DIM, 0, stream>>>(emb_out, cls, h);

    // ---- transformer layers ----
    for (int l = 0; l < N_LAYERS; ++l) {
        gemm_abt<<<dim3(768 / 64, M_ROWS / 64), 256, 0, stream>>>(
            h, in_w + (size_t)l * 768 * E_DIM, in_b + (size_t)l * 768, nullptr,
            qkv, M_ROWS, 768, E_DIM, 0);
        attn<<<N_GRAPHS * N_HEADS, 320, 0, stream>>>(qkv, attno);
        gemm_abt<<<dim3(E_DIM / 64, M_ROWS / 64), 256, 0, stream>>>(
            attno, out_w + (size_t)l * E_DIM * E_DIM, out_b + (size_t)l * E_DIM, nullptr,
            tmp, M_ROWS, E_DIM, E_DIM, 0);
        ln_residual<<<M_ROWS, E_DIM, 0, stream>>>(h, tmp, ln1_g + l * E_DIM, ln1_be + l * E_DIM);
        gemm_abt<<<dim3(MLP / 64, M_ROWS / 64), 256, 0, stream>>>(
            h, lin1_w + (size_t)l * MLP * E_DIM, lin1_b + (size_t)l * MLP, nullptr,
            fbuf, M_ROWS, MLP, E_DIM, 1);
        gemm_abt<<<dim3(E_DIM / 64, M_ROWS / 64), 256, 0, stream>>>(
            fbuf, lin2_w + (size_t)l * E_DIM * MLP, lin2_b + (size_t)l * E_DIM, nullptr,
            tmp, M_ROWS, E_DIM, MLP, 0);
        ln_residual<<<M_ROWS, E_DIM, 0, stream>>>(h, tmp, ln2_g + l * E_DIM, ln2_be + l * E_DIM);
    }

    // ---- classifier on cls tokens ----
    fc_kernel<<<N_GRAPHS, E_DIM, 0, stream>>>(h, fc_w, fc_b, out);
}

// Round 2
// 1501.654 us; speedup vs baseline: 2.2524x; 2.2524x over previous
//
#include <hip/hip_runtime.h>
#include <cstddef>

#define N_NODES 16384
#define N_GRAPHS 64
#define NPG 256
#define F_IN 128
#define E_DIM 256
#define N_HEADS 8
#define DH 32
#define MLP 1024
#define N_LAYERS 4
#define N_CLASSES 10
#define N_EDGES 262144
#define S_LEN 257
#define M_ROWS (N_GRAPHS * S_LEN)   // 16448
#define M_PAD 16512                 // 129 * 128
#define LN_EPS 1e-5f

typedef __attribute__((ext_vector_type(8))) short bf16x8;   // 8 bf16 in 4 VGPRs
typedef __attribute__((ext_vector_type(4))) float f32x4;

__device__ inline unsigned short f2b1(float f) {
    unsigned u = __float_as_uint(f);
    unsigned r = (u + 0x7fffu + ((u >> 16) & 1u)) >> 16;
    return (unsigned short)r;
}

#define GLOBAL_LOAD_LDS16(g, l) \
    __builtin_amdgcn_global_load_lds((__attribute__((address_space(1))) const void*)(g), \
                                     (__attribute__((address_space(3))) void*)(l), 16, 0, 0)

// ---------------- fp32 -> bf16 conversion (vectorized) ----------------
__global__ void f2b4(const float* __restrict__ in, unsigned short* __restrict__ out, int n4) {
    int i = blockIdx.x * 256 + threadIdx.x;
    if (i < n4) {
        float4 v = ((const float4*)in)[i];
        ushort4 o;
        o.x = f2b1(v.x); o.y = f2b1(v.y); o.z = f2b1(v.z); o.w = f2b1(v.w);
        ((ushort4*)out)[i] = o;
    }
}

// ---------------- MFMA GEMM: C(M,N) = A(M,K) @ W(N,K)^T (+bias)(+add)(relu?) --------
// bf16 inputs, fp32 accumulate. 128x128 tile, BK=32, 256 threads = 4 waves,
// each wave computes 64x64 via 4x4 grid of 16x16x32 mfma. M%128==0, N%128==0, K%32==0.
__global__ __launch_bounds__(256) void gemm_mfma(
    const unsigned short* __restrict__ A, const unsigned short* __restrict__ W,
    const float* __restrict__ bias, const float* __restrict__ add,
    float* __restrict__ outF, unsigned short* __restrict__ outB,
    int M, int N, int K, int relu)
{
    __shared__ __align__(16) unsigned short As[128 * 32];
    __shared__ __align__(16) unsigned short Bs[128 * 32];
    const int tid = threadIdx.x;
    const int wave = tid >> 6;
    const int lane = tid & 63;
    const int bm = blockIdx.y * 128;
    const int bn = blockIdx.x * 128;

    // staging: 8 chunks of 1024B per tile; wave w handles chunks w and w+4.
    // chunk c covers LDS rows c*16 .. c*16+15; lane loads 16B at row c*16+(lane>>2), col (lane&3)*8
    const int srow = (lane >> 2);
    const int scol = (lane & 3) * 8;
    const size_t a_r0 = (size_t)(bm + wave * 16 + srow) * K + scol;
    const size_t b_r0 = (size_t)(bn + wave * 16 + srow) * K + scol;
    unsigned short* ldsA0 = &As[wave * 512];
    unsigned short* ldsA1 = &As[(wave + 4) * 512];
    unsigned short* ldsB0 = &Bs[wave * 512];
    unsigned short* ldsB1 = &Bs[(wave + 4) * 512];

    const int wm = (wave & 1) * 64;
    const int wn = (wave >> 1) * 64;
    const int fr = lane & 15;
    const int fk = (lane >> 4) * 8;

    f32x4 acc[4][4];
#pragma unroll
    for (int i = 0; i < 4; ++i)
#pragma unroll
        for (int j = 0; j < 4; ++j)
            acc[i][j] = (f32x4){0.f, 0.f, 0.f, 0.f};

    for (int k0 = 0; k0 < K; k0 += 32) {
        __syncthreads();   // previous compute done before overwrite
        GLOBAL_LOAD_LDS16(A + a_r0 + k0, ldsA0);
        GLOBAL_LOAD_LDS16(A + a_r0 + (size_t)64 * K + k0, ldsA1);
        GLOBAL_LOAD_LDS16(W + b_r0 + k0, ldsB0);
        GLOBAL_LOAD_LDS16(W + b_r0 + (size_t)64 * K + k0, ldsB1);
        __syncthreads();   // DMA drained, data visible

        bf16x8 a[4], b[4];
#pragma unroll
        for (int i = 0; i < 4; ++i)
            a[i] = *(const bf16x8*)&As[(wm + i * 16 + fr) * 32 + fk];
#pragma unroll
        for (int j = 0; j < 4; ++j)
            b[j] = *(const bf16x8*)&Bs[(wn + j * 16 + fr) * 32 + fk];
#pragma unroll
        for (int i = 0; i < 4; ++i)
#pragma unroll
            for (int j = 0; j < 4; ++j)
                acc[i][j] = __builtin_amdgcn_mfma_f32_16x16x32_bf16(a[i], b[j], acc[i][j], 0, 0, 0);
    }

    // epilogue: D row=(lane>>4)*4+reg, col=lane&15
    const int er = (lane >> 4) * 4;
    const int ec = lane & 15;
#pragma unroll
    for (int j = 0; j < 4; ++j) {
        const int col = bn + wn + j * 16 + ec;
        const float bs = bias ? bias[col] : 0.f;
#pragma unroll
        for (int i = 0; i < 4; ++i) {
#pragma unroll
            for (int r = 0; r < 4; ++r) {
                const int row = bm + wm + i * 16 + er + r;
                float v = acc[i][j][r] + bs;
                if (add)  v += add[(size_t)row * N + col];
                if (relu) v = fmaxf(v, 0.f);
                if (outF) outF[(size_t)row * N + col] = v;
                if (outB) outB[(size_t)row * N + col] = f2b1(v);
            }
        }
    }
}

// ---------------- GCN pieces ----------------
__global__ void deg_count(const int* __restrict__ ei, float* __restrict__ deg) {
    int e = blockIdx.x * blockDim.x + threadIdx.x;
    if (e < N_EDGES) atomicAdd(&deg[ei[N_EDGES + e]], 1.0f);
}

__global__ void make_dinv(float* __restrict__ deg) {
    int i = blockIdx.x * blockDim.x + threadIdx.x;
    if (i < N_NODES) deg[i] = rsqrtf(deg[i] + 1.0f);  // +1 self loop
}

__global__ void edge_agg(const float* __restrict__ xw, const float* __restrict__ dinv,
                         const int* __restrict__ ei, float* __restrict__ agg) {
    int e = blockIdx.x;
    int f = threadIdx.x;  // 128
    int r = ei[e];
    int c = ei[N_EDGES + e];
    float nrm = dinv[r] * dinv[c];
    atomicAdd(&agg[(size_t)c * F_IN + f], nrm * xw[(size_t)r * F_IN + f]);
}

__global__ void gcn_finish(const float* __restrict__ agg, const float* __restrict__ xw,
                           const float* __restrict__ dinv, const float* __restrict__ b,
                           unsigned short* __restrict__ aggb) {
    int i = blockIdx.x;
    int f = threadIdx.x;  // 128
    float di = dinv[i];
    size_t idx = (size_t)i * F_IN + f;
    float v = agg[idx] + di * di * xw[idx] + b[f];
    aggb[idx] = f2b1(fmaxf(v, 0.f));
}

// ---------------- h assembly ----------------
__global__ void assemble_h(const float* __restrict__ emb, const float* __restrict__ cls,
                           float* __restrict__ h, unsigned short* __restrict__ hb) {
    int row = blockIdx.x;            // 0..16447
    int f = threadIdx.x;             // 256
    int g = row / S_LEN, s = row % S_LEN;
    float v = (s == 0) ? cls[f] : emb[((size_t)g * NPG + (s - 1)) * E_DIM + f];
    h[(size_t)row * E_DIM + f] = v;
    hb[(size_t)row * E_DIM + f] = f2b1(v);
}

// ---------------- attention: one block per (graph, head), bf16 output --------------
__global__ __launch_bounds__(320) void attn(const float* __restrict__ qkv,
                                            unsigned short* __restrict__ ob) {
    const int g = blockIdx.x >> 3;
    const int hh = blockIdx.x & 7;
    __shared__ float ks[S_LEN][DH];
    __shared__ float vs[S_LEN][DH];
    const float* base = qkv + (size_t)g * S_LEN * 768;
    for (int idx = threadIdx.x; idx < S_LEN * DH; idx += 320) {
        int s = idx >> 5, d = idx & 31;
        ks[s][d] = base[(size_t)s * 768 + 256 + hh * DH + d];
        vs[s][d] = base[(size_t)s * 768 + 512 + hh * DH + d];
    }
    __syncthreads();
    const int r = threadIdx.x;
    if (r < S_LEN) {
        float q[DH];
#pragma unroll
        for (int d = 0; d < DH; ++d) q[d] = base[(size_t)r * 768 + hh * DH + d];
        const float scale = 0.17677669529663687f;  // 1/sqrt(32)
        float m = -1e30f, l = 0.f;
        float acc[DH];
#pragma unroll
        for (int d = 0; d < DH; ++d) acc[d] = 0.f;
        for (int s = 0; s < S_LEN; ++s) {
            float dot = 0.f;
#pragma unroll
            for (int d = 0; d < DH; ++d) dot += q[d] * ks[s][d];
            dot *= scale;
            float mn = fmaxf(m, dot);
            float alpha = __expf(m - mn);
            float p = __expf(dot - mn);
            l = l * alpha + p;
#pragma unroll
            for (int d = 0; d < DH; ++d) acc[d] = acc[d] * alpha + p * vs[s][d];
            m = mn;
        }
        float inv = 1.f / l;
        unsigned short* orow = ob + ((size_t)g * S_LEN + r) * E_DIM + hh * DH;
#pragma unroll
        for (int d = 0; d < DH; ++d) orow[d] = f2b1(acc[d] * inv);
    }
}

// ---------------- LayerNorm(h + res) in-place on h, also writes bf16 copy ----------
__global__ __launch_bounds__(256) void ln_residual(float* __restrict__ h, const float* __restrict__ res,
                                                   const float* __restrict__ g, const float* __restrict__ b,
                                                   unsigned short* __restrict__ hb) {
    __shared__ float ws1[4], ws2[4];
    __shared__ float mu_s, rstd_s;
    const int row = blockIdx.x;
    const int t = threadIdx.x;
    size_t idx = (size_t)row * E_DIM + t;
    float v = h[idx] + res[idx];
    float s1 = v, s2 = v * v;
#pragma unroll
    for (int off = 32; off > 0; off >>= 1) {
        s1 += __shfl_down(s1, off, 64);
        s2 += __shfl_down(s2, off, 64);
    }
    int wid = t >> 6, lane = t & 63;
    if (lane == 0) { ws1[wid] = s1; ws2[wid] = s2; }
    __syncthreads();
    if (t == 0) {
        float a1 = ws1[0] + ws1[1] + ws1[2] + ws1[3];
        float a2 = ws2[0] + ws2[1] + ws2[2] + ws2[3];
        float mu = a1 * (1.f / 256.f);
        float var = a2 * (1.f / 256.f) - mu * mu;
        mu_s = mu;
        rstd_s = rsqrtf(var + LN_EPS);
    }
    __syncthreads();
    float o = (v - mu_s) * rstd_s * g[t] + b[t];
    h[idx] = o;
    hb[idx] = f2b1(o);
}

// ---------------- final classifier ----------------
__global__ void fc_kernel(const float* __restrict__ h, const float* __restrict__ w,
                          const float* __restrict__ b, float* __restrict__ out) {
    int g = blockIdx.x;
    __shared__ float row[E_DIM];
    int t = threadIdx.x;
    row[t] = h[(size_t)g * S_LEN * E_DIM + t];
    __syncthreads();
    if (t < N_CLASSES) {
        float s = 0.f;
        for (int j = 0; j < E_DIM; ++j) s += row[j] * w[t * E_DIM + j];
        out[g * N_CLASSES + t] = s + b[t];
    }
}

extern "C" void kernel_launch(void* const* d_in, const int* in_sizes, int n_in,
                              void* d_out, int out_size, void* d_ws, size_t ws_size,
                              hipStream_t stream) {
    const float* x       = (const float*)d_in[0];
    const int*   edgei   = (const int*)  d_in[1];
    const float* pos_enc = (const float*)d_in[3];
    const float* gcn_w   = (const float*)d_in[4];
    const float* gcn_b   = (const float*)d_in[5];
    const float* cls     = (const float*)d_in[6];
    const float* emb_w   = (const float*)d_in[7];
    const float* emb_b   = (const float*)d_in[8];
    const float* in_w    = (const float*)d_in[9];
    const float* in_b    = (const float*)d_in[10];
    const float* out_w   = (const float*)d_in[11];
    const float* out_b   = (const float*)d_in[12];
    const float* lin1_w  = (const float*)d_in[13];
    const float* lin1_b  = (const float*)d_in[14];
    const float* lin2_w  = (const float*)d_in[15];
    const float* lin2_b  = (const float*)d_in[16];
    const float* ln1_g   = (const float*)d_in[17];
    const float* ln1_be  = (const float*)d_in[18];
    const float* ln2_g   = (const float*)d_in[19];
    const float* ln2_be  = (const float*)d_in[20];
    const float* fc_w    = (const float*)d_in[21];
    const float* fc_b    = (const float*)d_in[22];
    float* out = (float*)d_out;

    // ---- workspace layout ----
    float* ws = (float*)d_ws;
    float* h    = ws;                       // M_PAD*256
    float* tmp  = h    + (size_t)M_PAD * E_DIM;
    float* qkv  = tmp  + (size_t)M_PAD * E_DIM;    // M_PAD*768
    float* xw   = qkv  + (size_t)M_PAD * 768;      // 16384*128
    float* agg  = xw   + (size_t)N_NODES * F_IN;
    float* deg  = agg  + (size_t)N_NODES * F_IN;   // 16384
    unsigned short* ub     = (unsigned short*)(deg + N_NODES);
    unsigned short* hb     = ub;                                  // M_PAD*256
    unsigned short* attnob = hb     + (size_t)M_PAD * E_DIM;      // M_PAD*256
    unsigned short* fbufb  = attnob + (size_t)M_PAD * E_DIM;      // M_PAD*1024
    unsigned short* xb     = fbufb  + (size_t)M_PAD * MLP;        // 16384*128
    unsigned short* aggb   = xb     + (size_t)N_NODES * F_IN;     // 16384*128
    unsigned short* gcn_wb = aggb   + (size_t)N_NODES * F_IN;     // 128*128
    unsigned short* emb_wb = gcn_wb + (size_t)F_IN * F_IN;        // 256*128
    unsigned short* in_wb  = emb_wb + (size_t)E_DIM * F_IN;       // 4*768*256
    unsigned short* out_wb = in_wb  + (size_t)N_LAYERS * 768 * E_DIM;
    unsigned short* lin1_wb= out_wb + (size_t)N_LAYERS * E_DIM * E_DIM;
    unsigned short* lin2_wb= lin1_wb+ (size_t)N_LAYERS * MLP * E_DIM;
    float* emb_out = qkv;   // alias, free before transformer loop

    // ---- weight / input conversions to bf16 ----
    f2b4<<<(N_NODES * F_IN / 4 + 255) / 256, 256, 0, stream>>>(x, xb, N_NODES * F_IN / 4);
    f2b4<<<(F_IN * F_IN / 4 + 255) / 256, 256, 0, stream>>>(gcn_w, gcn_wb, F_IN * F_IN / 4);
    f2b4<<<(E_DIM * F_IN / 4 + 255) / 256, 256, 0, stream>>>(emb_w, emb_wb, E_DIM * F_IN / 4);
    f2b4<<<(N_LAYERS * 768 * E_DIM / 4 + 255) / 256, 256, 0, stream>>>(in_w, in_wb, N_LAYERS * 768 * E_DIM / 4);
    f2b4<<<(N_LAYERS * E_DIM * E_DIM / 4 + 255) / 256, 256, 0, stream>>>(out_w, out_wb, N_LAYERS * E_DIM * E_DIM / 4);
    f2b4<<<(N_LAYERS * MLP * E_DIM / 4 + 255) / 256, 256, 0, stream>>>(lin1_w, lin1_wb, N_LAYERS * MLP * E_DIM / 4);
    f2b4<<<(N_LAYERS * E_DIM * MLP / 4 + 255) / 256, 256, 0, stream>>>(lin2_w, lin2_wb, N_LAYERS * E_DIM * MLP / 4);

    // ---- GCN ----
    hipMemsetAsync(deg, 0, N_NODES * sizeof(float), stream);
    hipMemsetAsync(agg, 0, (size_t)N_NODES * F_IN * sizeof(float), stream);
    deg_count<<<(N_EDGES + 255) / 256, 256, 0, stream>>>(edgei, deg);
    make_dinv<<<(N_NODES + 255) / 256, 256, 0, stream>>>(deg);
    gemm_mfma<<<dim3(F_IN / 128, N_NODES / 128), 256, 0, stream>>>(
        xb, gcn_wb, nullptr, nullptr, xw, nullptr, N_NODES, F_IN, F_IN, 0);
    edge_agg<<<N_EDGES, F_IN, 0, stream>>>(xw, deg, edgei, agg);
    gcn_finish<<<N_NODES, F_IN, 0, stream>>>(agg, xw, deg, gcn_b, aggb);

    // ---- embedding + pos_enc ----
    gemm_mfma<<<dim3(E_DIM / 128, N_NODES / 128), 256, 0, stream>>>(
        aggb, emb_wb, emb_b, pos_enc, emb_out, nullptr, N_NODES, E_DIM, F_IN, 0);
    assemble_h<<<M_ROWS, E_DIM, 0, stream>>>(emb_out, cls, h, hb);

    // ---- transformer layers ----
    for (int l = 0; l < N_LAYERS; ++l) {
        gemm_mfma<<<dim3(768 / 128, M_PAD / 128), 256, 0, stream>>>(
            hb, in_wb + (size_t)l * 768 * E_DIM, in_b + (size_t)l * 768, nullptr,
            qkv, nullptr, M_PAD, 768, E_DIM, 0);
        attn<<<N_GRAPHS * N_HEADS, 320, 0, stream>>>(qkv, attnob);
        gemm_mfma<<<dim3(E_DIM / 128, M_PAD / 128), 256, 0, stream>>>(
            attnob, out_wb + (size_t)l * E_DIM * E_DIM, out_b + (size_t)l * E_DIM, nullptr,
            tmp, nullptr, M_PAD, E_DIM, E_DIM, 0);
        ln_residual<<<M_ROWS, E_DIM, 0, stream>>>(h, tmp, ln1_g + l * E_DIM, ln1_be + l * E_DIM, hb);
        gemm_mfma<<<dim3(MLP / 128, M_PAD / 128), 256, 0, stream>>>(
            hb, lin1_wb + (size_t)l * MLP * E_DIM, lin1_b + (size_t)l * MLP, nullptr,
            nullptr, fbufb, M_PAD, MLP, E_DIM, 1);
        gemm_mfma<<<dim3(E_DIM / 128, M_PAD / 128), 256, 0, stream>>>(
            fbufb, lin2_wb + (size_t)l * E_DIM * MLP, lin2_b + (size_t)l * E_DIM, nullptr,
            tmp, nullptr, M_PAD, E_DIM, MLP, 0);
        ln_residual<<<M_ROWS, E_DIM, 0, stream>>>(h, tmp, ln2_g + l * E_DIM, ln2_be + l * E_DIM, hb);
    }

    // ---- classifier on cls tokens ----
    fc_kernel<<<N_GRAPHS, E_DIM, 0, stream>>>(h, fc_w, fc_b, out);
}